// Round 6
// baseline (151.853 us; speedup 1.0000x reference)
//
#include <hip/hip_runtime.h>
#include <math.h>

#define HDIM 512
#define LSEQ 1024
#define BSZ  4

typedef __attribute__((ext_vector_type(8))) short short8;
typedef __attribute__((ext_vector_type(4))) float floatx4;
typedef _Float16 half8 __attribute__((ext_vector_type(8)));

__device__ __forceinline__ float2 cmul(float2 a, float2 b) {
  float2 r;
  r.x = a.x * b.x - a.y * b.y;
  r.y = a.x * b.y + a.y * b.x;
  return r;
}
__device__ __forceinline__ float2 cadd(float2 a, float2 b) {
  float2 r; r.x = a.x + b.x; r.y = a.y + b.y; return r;
}
__device__ __forceinline__ float2 cfma(float2 a, float2 b, float2 c) {
  c.x += a.x * b.x - a.y * b.y;
  c.y += a.x * b.y + a.y * b.x;
  return c;
}
__device__ __forceinline__ ushort f2h(float f) {
  _Float16 h = (_Float16)f;
  return *(ushort*)&h;
}
__device__ __forceinline__ uint pack2h(float a, float b) {
  return (uint)f2h(a) | ((uint)f2h(b) << 16);
}

// ====== Stage 1: block 0 = kgen; blocks 1..456 = LayerNorm(->fp16) + wconv ======
__global__ __launch_bounds__(576) void stage1_kernel(
    const float* __restrict__ x, const float* __restrict__ nw,
    const float* __restrict__ nb, ushort* __restrict__ xn16,
    const float* __restrict__ lre, const float* __restrict__ lim,
    const float* __restrict__ pre, const float* __restrict__ pim,
    const float* __restrict__ bre, const float* __restrict__ bim,
    const float* __restrict__ cre, const float* __restrict__ cim,
    const float* __restrict__ logstep, float* __restrict__ Kout,
    const float* __restrict__ w1, const float* __restrict__ w2,
    ushort* __restrict__ Wst) {
  __shared__ float2 Ldab[64], Lu[64], Lr[64], LBb[64];
  __shared__ float2 Rv[2048];     // [a*64+n] = (c^T (Ab^32)^a)[n]
  __shared__ float2 Wv[2048];     // [n*32+b] = (Ab^b Bb)[n]
  int tid = threadIdx.x;
  int wv = tid >> 6;              // wave 0..8
  int lane = tid & 63;

  if (blockIdx.x != 0) {
    // ---- LayerNorm: 9 rows per block, one wave per row; fp16 output ----
    int row = (blockIdx.x - 1) * 9 + wv;
    if (row < BSZ * LSEQ) {
      const float* xr = x + (size_t)row * HDIM;
      float4 v0 = ((const float4*)xr)[lane];
      float4 v1 = ((const float4*)xr)[lane + 64];
      float s  = v0.x + v0.y + v0.z + v0.w + v1.x + v1.y + v1.z + v1.w;
      float ss = v0.x*v0.x + v0.y*v0.y + v0.z*v0.z + v0.w*v0.w
               + v1.x*v1.x + v1.y*v1.y + v1.z*v1.z + v1.w*v1.w;
      #pragma unroll
      for (int m = 1; m < 64; m <<= 1) { s += __shfl_xor(s, m); ss += __shfl_xor(ss, m); }
      float mu   = s * (1.0f / HDIM);
      float var  = ss * (1.0f / HDIM) - mu * mu;
      float rstd = rsqrtf(var + 1e-5f);
      float4 w0 = ((const float4*)nw)[lane];
      float4 w1v = ((const float4*)nw)[lane + 64];
      float4 b0 = ((const float4*)nb)[lane];
      float4 b1 = ((const float4*)nb)[lane + 64];
      float4 o0, o1;
      o0.x = (v0.x - mu) * rstd * w0.x + b0.x;
      o0.y = (v0.y - mu) * rstd * w0.y + b0.y;
      o0.z = (v0.z - mu) * rstd * w0.z + b0.z;
      o0.w = (v0.w - mu) * rstd * w0.w + b0.w;
      o1.x = (v1.x - mu) * rstd * w1v.x + b1.x;
      o1.y = (v1.y - mu) * rstd * w1v.y + b1.y;
      o1.z = (v1.z - mu) * rstd * w1v.z + b1.z;
      o1.w = (v1.w - mu) * rstd * w1v.w + b1.w;
      ushort* xo = xn16 + (size_t)row * HDIM;
      uint2 p0, p1;
      p0.x = pack2h(o0.x, o0.y); p0.y = pack2h(o0.z, o0.w);
      p1.x = pack2h(o1.x, o1.y); p1.y = pack2h(o1.z, o1.w);
      *(uint2*)&xo[lane * 4]       = p0;
      *(uint2*)&xo[256 + lane * 4] = p1;
    }
    // ---- Weight convert (fills idle time while block 0 runs kgen) ----
    int idx = (blockIdx.x - 1) * 576 + tid;
    if (idx < 65536) {
      int e0 = idx * 8;
      int n = e0 >> 9, k0 = e0 & 511;
      const float* Wr = (n < 512) ? (w1 + (size_t)n * 512 + k0)
                                  : (w2 + (size_t)(n - 512) * 512 + k0);
      ushort tmp[8];
      #pragma unroll
      for (int q = 0; q < 8; q++) tmp[q] = f2h(Wr[q]);
      *(short8*)&Wst[e0] = *(short8*)tmp;
    }
    return;
  }

  // ================= block 0: K generation =================
  if (tid < 64) {
    int n = tid;
    float step = expf(logstep[0]);
    float g = 2.0f / step;
    float lr = lre[n], li = lim[n];
    float pr = pre[n], pi = pim[n];
    float br = bre[n], bi = bim[n];
    float den  = (g - lr) * (g - lr) + li * li;
    float dinr = (g - lr) / den, dini = li / den;
    float dabr = (g + lr) * dinr - li * dini;
    float dabi = (g + lr) * dini + li * dinr;
    float ur = dinr * pr - dini * pi;
    float ui = dinr * pi + dini * pr;
    float qr = pr * dinr + pi * dini;
    float qi = pr * dini - pi * dinr;
    float pm2 = pr * pr + pi * pi;
    float betr = pm2 * dinr, beti = pm2 * dini;
    float gar = qr * br - qi * bi;
    float gai = qr * bi + qi * br;
    #pragma unroll
    for (int m = 1; m < 64; m <<= 1) {
      betr += __shfl_xor(betr, m); beti += __shfl_xor(beti, m);
      gar  += __shfl_xor(gar, m);  gai  += __shfl_xor(gai, m);
    }
    float obr = 1.0f + betr, obi = beti;
    float ob2 = obr * obr + obi * obi;
    float kr = -2.0f * g * obr / ob2;
    float ki =  2.0f * g * obi / ob2;
    float rr = kr * qr - ki * qi;
    float ri = kr * qi + ki * qr;
    float tgr = (gar * obr + gai * obi) / ob2;
    float tgi = (gai * obr - gar * obi) / ob2;
    float dbr = dinr * br - dini * bi;
    float dbi = dinr * bi + dini * br;
    float Bbr = 2.0f * (dbr - (ur * tgr - ui * tgi));
    float Bbi = 2.0f * (dbi - (ur * tgi + ui * tgr));
    float2 t;
    t.x = dabr; t.y = dabi; Ldab[n] = t;
    t.x = ur;   t.y = ui;   Lu[n]   = t;
    t.x = rr;   t.y = ri;   Lr[n]   = t;
    t.x = Bbr;  t.y = Bbi;  LBb[n]  = t;
  }
  if (wv == 8) { float2 cc; cc.x = cre[lane]; cc.y = cim[lane]; Rv[lane] = cc; }
  __syncthreads();

  int g8 = lane >> 3;
  int q8 = lane & 7;
  int jm = wv * 8 + g8;
  float2 cv[8];

  if (wv < 8) {
    // Phase B: barrier-free column chains
    float2 dab[8], u[8], rn[8];
    #pragma unroll
    for (int ii = 0; ii < 8; ii++) {
      int n = q8 * 8 + ii;
      dab[ii] = Ldab[n]; u[ii] = Lu[n]; rn[ii] = Lr[n];
    }
    float2 rj = Lr[jm];
    #pragma unroll
    for (int ii = 0; ii < 8; ii++) {
      int n = q8 * 8 + ii;
      cv[ii] = cmul(u[ii], rj);
      if (n == jm) cv[ii] = cadd(cv[ii], dab[ii]);
    }
    for (int s = 0; s < 31; s++) {
      float2 part; part.x = 0.f; part.y = 0.f;
      #pragma unroll
      for (int ii = 0; ii < 8; ii++) part = cfma(rn[ii], cv[ii], part);
      #pragma unroll
      for (int m = 1; m < 8; m <<= 1) {
        part.x += __shfl_xor(part.x, m);
        part.y += __shfl_xor(part.y, m);
      }
      #pragma unroll
      for (int ii = 0; ii < 8; ii++) {
        float2 nc = cmul(dab[ii], cv[ii]);
        cv[ii] = cfma(u[ii], part, nc);
      }
    }
  } else {
    // Phase D (concurrent): W chain
    float2 dab0 = Ldab[lane], u0 = Lu[lane], r0 = Lr[lane];
    float2 w = LBb[lane];
    Wv[lane * 32 + 0] = w;
    for (int b = 1; b < 32; b++) {
      float dr = r0.x * w.x - r0.y * w.y;
      float di = r0.x * w.y + r0.y * w.x;
      #pragma unroll
      for (int m = 1; m < 64; m <<= 1) { dr += __shfl_xor(dr, m); di += __shfl_xor(di, m); }
      float2 nw2;
      nw2.x = dab0.x * w.x - dab0.y * w.y + u0.x * dr - u0.y * di;
      nw2.y = dab0.x * w.y + dab0.y * w.x + u0.x * di + u0.y * dr;
      w = nw2;
      Wv[lane * 32 + b] = w;
    }
  }
  __syncthreads();

  // Phase C: R chain
  for (int a = 1; a < 32; a++) {
    if (wv < 8) {
      float2 part; part.x = 0.f; part.y = 0.f;
      #pragma unroll
      for (int ii = 0; ii < 8; ii++) {
        float2 Rk = Rv[(a - 1) * 64 + q8 * 8 + ii];
        part = cfma(Rk, cv[ii], part);
      }
      #pragma unroll
      for (int m = 1; m < 8; m <<= 1) {
        part.x += __shfl_xor(part.x, m);
        part.y += __shfl_xor(part.y, m);
      }
      if (q8 == 0) Rv[a * 64 + jm] = part;
    }
    __syncthreads();
  }

  // Phase E
  for (int midx = tid; midx < 1024; midx += 576) {
    int a = midx >> 5, b = midx & 31;
    float acc = 0.f;
    for (int n = 0; n < 64; n++) {
      float2 R = Rv[a * 64 + n];
      float2 W = Wv[n * 32 + b];
      acc += R.x * W.x - R.y * W.y;
    }
    Kout[midx] = acc;
  }
}

// ------- Prep: transpose(xn16->Uhi, fp16 in/out) + toeplitz(K->Thi, guarded) -------
// blocks [0,512): transpose; [512,1024): toeplitz.
__global__ __launch_bounds__(256) void prep_kernel(
    const ushort* __restrict__ xn16, const float* __restrict__ K,
    ushort* __restrict__ Uhi, ushort* __restrict__ Thi) {
  __shared__ __attribute__((aligned(16))) ushort tile[64][72];
  int blk = blockIdx.x;
  int tid = threadIdx.x;
  if (blk < 512) {
    int ht = blk & 7, lt = (blk >> 3) & 15, b = blk >> 7;
    int r = tid >> 2;               // 0..63 (t' within tile)
    int sc = (tid & 3) * 16;        // 0,16,32,48 (h within tile)
    const ushort* src = xn16 + ((size_t)(b * LSEQ + lt * 64 + r)) * HDIM + ht * 64 + sc;
    uint4 va = *(const uint4*)&src[0];
    uint4 vb = *(const uint4*)&src[8];
    *(uint4*)&tile[r][sc]     = va;
    *(uint4*)&tile[r][sc + 8] = vb;
    __syncthreads();
    // output: row = h, cols = t' (16 per thread, packed stores)
    int hr = tid >> 2;              // 0..63 (h within tile)
    int c0 = (tid & 3) * 16;        // t' chunk
    ushort tmp[16];
    #pragma unroll
    for (int q = 0; q < 16; q++) tmp[q] = tile[c0 + q][hr];
    ushort* dst = Uhi + ((size_t)(b * HDIM + ht * 64 + hr)) * LSEQ + lt * 64 + c0;
    *(uint4*)&dst[0] = *(uint4*)&tmp[0];
    *(uint4*)&dst[8] = *(uint4*)&tmp[8];
  } else {
    int r = blk - 512;                              // 0..511
    int t = r * 2 + (tid >> 7);
    int tau0 = (tid & 127) * 8;
    int bound = ((t >> 6) + 1) << 6;                // conv never reads tau >= bound
    if (tau0 < bound) {
      ushort hi[8];
      #pragma unroll
      for (int q = 0; q < 8; q++) {
        int tau = tau0 + q;
        float v = (tau <= t) ? K[t - tau] : 0.f;
        hi[q] = f2h(v);
      }
      *(short8*)&Thi[(size_t)t * 1024 + tau0] = *(short8*)hi;
    }
  }
}

// -------- Conv GEMM: fp16, K_STEP=64, dbuf LDS, depth-1 named-reg prefetch ----
__global__ __launch_bounds__(256) void conv_gemm_kernel(
    const ushort* __restrict__ Thi, const ushort* __restrict__ Uhi,
    const ushort* __restrict__ xn16, const float* __restrict__ dptr,
    ushort* __restrict__ A) {
  // per set: [T][U], each 64 rows x 72 halfs (64 + 8 pad) = 4608 -> 9216 ushorts/set
  __shared__ __attribute__((aligned(16))) ushort sbuf[2 * 9216];
  int tid = threadIdx.x;
  int lane = tid & 63;
  int wv = tid >> 6;
  int wm = wv >> 1, wn = wv & 1;
  int by = blockIdx.y;                    // 0..15
  int bm = (by < 8) ? by : 23 - by;       // balanced pairing across CUs
  int bn = blockIdx.x;                    // 0..31
  floatx4 acc[2][2] = {};
  int srow = tid >> 2;                    // 0..63
  int scol = (tid & 3) * 16;              // 0,16,32,48
  int ldst = srow * 72 + scol;
  int fr = lane & 15, fq = (lane >> 4) * 8;
  size_t Toff = (size_t)(bm * 64 + srow) * 1024 + scol;
  size_t Uoff = (size_t)(bn * 64 + srow) * 1024 + scol;
  int KT = bm + 1;                        // 64-wide k-tiles (tau <= t)
  // ---- prologue: stage tile 0 into set 0 ----
  uint4 t0 = *(const uint4*)&Thi[Toff];
  uint4 t1 = *(const uint4*)&Thi[Toff + 8];
  uint4 u0 = *(const uint4*)&Uhi[Uoff];
  uint4 u1 = *(const uint4*)&Uhi[Uoff + 8];
  *(uint4*)&sbuf[ldst]            = t0;
  *(uint4*)&sbuf[ldst + 8]        = t1;
  *(uint4*)&sbuf[ldst + 4608]     = u0;
  *(uint4*)&sbuf[ldst + 4608 + 8] = u1;
  __syncthreads();
  for (int kt = 0; kt < KT; kt++) {
    const ushort* src = sbuf + (kt & 1) * 9216;
    bool more = (kt + 1 < KT);
    if (more) {
      size_t k1 = (size_t)(kt + 1) * 64;
      t0 = *(const uint4*)&Thi[Toff + k1];
      t1 = *(const uint4*)&Thi[Toff + k1 + 8];
      u0 = *(const uint4*)&Uhi[Uoff + k1];
      u1 = *(const uint4*)&Uhi[Uoff + k1 + 8];
    }
    half8 ah[2][2], bh[2][2];
    #pragma unroll
    for (int i = 0; i < 2; i++) {
      int ar = (wm * 32 + i * 16 + fr) * 72;
      int br = 4608 + (wn * 32 + i * 16 + fr) * 72;
      ah[i][0] = *(const half8*)&src[ar + fq];
      ah[i][1] = *(const half8*)&src[ar + 32 + fq];
      bh[i][0] = *(const half8*)&src[br + fq];
      bh[i][1] = *(const half8*)&src[br + 32 + fq];
    }
    #pragma unroll
    for (int ks = 0; ks < 2; ks++)
      #pragma unroll
      for (int i = 0; i < 2; i++)
        #pragma unroll
        for (int j = 0; j < 2; j++)
          acc[i][j] = __builtin_amdgcn_mfma_f32_16x16x32_f16(ah[i][ks], bh[j][ks], acc[i][j], 0, 0, 0);
    if (more) {
      ushort* dst = sbuf + ((kt & 1) ^ 1) * 9216;
      *(uint4*)&dst[ldst]            = t0;
      *(uint4*)&dst[ldst + 8]        = t1;
      *(uint4*)&dst[ldst + 4608]     = u0;
      *(uint4*)&dst[ldst + 4608 + 8] = u1;
      __syncthreads();
    }
  }
  float d = dptr[0];
  int row0 = bm * 64 + wm * 32;
  int col0 = bn * 64 + wn * 32;
  int fc = lane & 15, frq = (lane >> 4) * 4;
  #pragma unroll
  for (int i = 0; i < 2; i++)
    #pragma unroll
    for (int j = 0; j < 2; j++)
      #pragma unroll
      for (int r = 0; r < 4; r++) {
        int t = row0 + i * 16 + frq + r;
        int c = col0 + j * 16 + fc;
        int b = c >> 9, h = c & 511;
        size_t off = (size_t)(b * LSEQ + t) * HDIM + h;
        float xv = (float)(*(const _Float16*)&xn16[off]);
        float y = acc[i][j][r] + d * xv;
        // gelu(y) = y * sigmoid(2z), z = 0.79788456*(y+0.044715*y^3)
        float z2 = 1.5957691216057308f * y * (1.0f + 0.044715f * y * y);
        float sg = __builtin_amdgcn_rcpf(1.0f + __expf(-z2));
        A[off] = f2h(y * sg);
      }
}

// ---- Proj GEMM: fp16, K_STEP=64, dbuf LDS, depth-1 named-reg prefetch, gated epilogue ----
__global__ __launch_bounds__(256) void proj_kernel(
    const ushort* __restrict__ Abuf, const ushort* __restrict__ Wst,
    const float* __restrict__ x, const float* __restrict__ ob,
    const float* __restrict__ o2b, float* __restrict__ out) {
  // per set: [A][W1][W2], each 64 x 72 halfs = 4608 -> 13824 ushorts/set
  __shared__ __attribute__((aligned(16))) ushort sbuf[2 * 13824];
  int tid = threadIdx.x;
  int lane = tid & 63;
  int wv = tid >> 6;
  int wm = wv >> 1, wn = wv & 1;
  int bm = blockIdx.y, bn = blockIdx.x;   // bm<64, bn<8
  int srow = tid >> 2;                    // 0..63
  int scol = (tid & 3) * 16;              // 0,16,32,48
  int ldst = srow * 72 + scol;
  int fr = lane & 15, fq = (lane >> 4) * 8;
  floatx4 acc1[2][2] = {}, acc2[2][2] = {};
  size_t Aoff  = (size_t)(bm * 64 + srow) * 512 + scol;
  size_t W1off = (size_t)(bn * 64 + srow) * 512 + scol;
  size_t W2off = W1off + (size_t)512 * 512;
  // ---- prologue: stage tile 0 into set 0 ----
  uint4 a0 = *(const uint4*)&Abuf[Aoff];
  uint4 a1 = *(const uint4*)&Abuf[Aoff + 8];
  uint4 v0 = *(const uint4*)&Wst[W1off];
  uint4 v1 = *(const uint4*)&Wst[W1off + 8];
  uint4 v2 = *(const uint4*)&Wst[W2off];
  uint4 v3 = *(const uint4*)&Wst[W2off + 8];
  *(uint4*)&sbuf[ldst]            = a0;
  *(uint4*)&sbuf[ldst + 8]        = a1;
  *(uint4*)&sbuf[ldst + 4608]     = v0;
  *(uint4*)&sbuf[ldst + 4608 + 8] = v1;
  *(uint4*)&sbuf[ldst + 9216]     = v2;
  *(uint4*)&sbuf[ldst + 9216 + 8] = v3;
  __syncthreads();
  for (int kt = 0; kt < 8; kt++) {
    const ushort* src = sbuf + (kt & 1) * 13824;
    bool more = (kt + 1 < 8);
    if (more) {
      int k1 = (kt + 1) * 64;
      a0 = *(const uint4*)&Abuf[Aoff + k1];
      a1 = *(const uint4*)&Abuf[Aoff + k1 + 8];
      v0 = *(const uint4*)&Wst[W1off + k1];
      v1 = *(const uint4*)&Wst[W1off + k1 + 8];
      v2 = *(const uint4*)&Wst[W2off + k1];
      v3 = *(const uint4*)&Wst[W2off + k1 + 8];
    }
    half8 af[2][2], b1[2][2], b2[2][2];
    #pragma unroll
    for (int i = 0; i < 2; i++) {
      int ar  = (wm * 32 + i * 16 + fr) * 72;
      int wr1 = 4608 + (wn * 32 + i * 16 + fr) * 72;
      int wr2 = 9216 + (wn * 32 + i * 16 + fr) * 72;
      af[i][0] = *(const half8*)&src[ar + fq];
      af[i][1] = *(const half8*)&src[ar + 32 + fq];
      b1[i][0] = *(const half8*)&src[wr1 + fq];
      b1[i][1] = *(const half8*)&src[wr1 + 32 + fq];
      b2[i][0] = *(const half8*)&src[wr2 + fq];
      b2[i][1] = *(const half8*)&src[wr2 + 32 + fq];
    }
    #pragma unroll
    for (int ks = 0; ks < 2; ks++)
      #pragma unroll
      for (int i = 0; i < 2; i++)
        #pragma unroll
        for (int j = 0; j < 2; j++) {
          acc1[i][j] = __builtin_amdgcn_mfma_f32_16x16x32_f16(af[i][ks], b1[j][ks], acc1[i][j], 0, 0, 0);
          acc2[i][j] = __builtin_amdgcn_mfma_f32_16x16x32_f16(af[i][ks], b2[j][ks], acc2[i][j], 0, 0, 0);
        }
    if (more) {
      ushort* dst = sbuf + ((kt & 1) ^ 1) * 13824;
      *(uint4*)&dst[ldst]            = a0;
      *(uint4*)&dst[ldst + 8]        = a1;
      *(uint4*)&dst[ldst + 4608]     = v0;
      *(uint4*)&dst[ldst + 4608 + 8] = v1;
      *(uint4*)&dst[ldst + 9216]     = v2;
      *(uint4*)&dst[ldst + 9216 + 8] = v3;
      __syncthreads();
    }
  }
  int row0 = bm * 64 + wm * 32;
  int col0 = bn * 64 + wn * 32;
  int fc = lane & 15, frq = (lane >> 4) * 4;
  #pragma unroll
  for (int i = 0; i < 2; i++)
    #pragma unroll
    for (int j = 0; j < 2; j++)
      #pragma unroll
      for (int r = 0; r < 4; r++) {
        int row = row0 + i * 16 + frq + r;
        int col = col0 + j * 16 + fc;
        float c1 = acc1[i][j][r] + ob[col];
        float c2 = acc2[i][j][r] + o2b[col];
        float gate = __builtin_amdgcn_rcpf(1.0f + __expf(-c2));
        size_t off = (size_t)row * HDIM + col;
        out[off] = x[off] + c1 * gate;
      }
}

extern "C" void kernel_launch(void* const* d_in, const int* in_sizes, int n_in,
                              void* d_out, int out_size, void* d_ws, size_t ws_size,
                              hipStream_t stream) {
  const float* x   = (const float*)d_in[0];
  const float* nw  = (const float*)d_in[1];
  const float* nb  = (const float*)d_in[2];
  const float* lre = (const float*)d_in[3];
  const float* lim = (const float*)d_in[4];
  const float* pre = (const float*)d_in[5];
  const float* pim = (const float*)d_in[6];
  const float* bre = (const float*)d_in[7];
  const float* bim = (const float*)d_in[8];
  const float* cre = (const float*)d_in[9];
  const float* cim = (const float*)d_in[10];
  const float* dsc = (const float*)d_in[11];
  const float* lst = (const float*)d_in[12];
  const float* w1  = (const float*)d_in[13];
  const float* ob  = (const float*)d_in[14];
  const float* w2  = (const float*)d_in[15];
  const float* o2b = (const float*)d_in[16];

  char* ws = (char*)d_ws;
  ushort* xn16 = (ushort*)(ws);                         // 0..4MB  (fp16 LN output)
  ushort* Uhi  = (ushort*)(ws + (size_t)(8  << 20));    // 8..12MB  (fp16)
  ushort* Thi  = (ushort*)(ws + (size_t)(12 << 20));    // 12..14MB (fp16)
  ushort* Wst  = (ushort*)(ws + (size_t)(16 << 20));    // 16..17MB (fp16)
  ushort* Abuf = (ushort*)(ws + (size_t)(17 << 20));    // 17..21MB (fp16)
  float* Kbuf  = (float*)(ws + (size_t)(21 << 20));     // 4KB
  float* out   = (float*)d_out;

  stage1_kernel<<<dim3(457), dim3(576), 0, stream>>>(x, nw, nb, xn16,
                                                     lre, lim, pre, pim, bre, bim,
                                                     cre, cim, lst, Kbuf,
                                                     w1, w2, Wst);
  prep_kernel<<<dim3(1024), dim3(256), 0, stream>>>(xn16, Kbuf, Uhi, Thi);
  conv_gemm_kernel<<<dim3(32, 16), dim3(256), 0, stream>>>(Thi, Uhi,
                                                           xn16, dsc, Abuf);
  proj_kernel<<<dim3(8, 64), dim3(256), 0, stream>>>(Abuf, Wst, x, ob, o2b, out);
}

// Round 7
// 147.380 us; speedup vs baseline: 1.0304x; 1.0304x over previous
//
#include <hip/hip_runtime.h>
#include <math.h>

#define HDIM 512
#define LSEQ 1024
#define BSZ  4

typedef __attribute__((ext_vector_type(8))) short short8;
typedef __attribute__((ext_vector_type(4))) float floatx4;
typedef _Float16 half8 __attribute__((ext_vector_type(8)));

__device__ __forceinline__ float2 cmul(float2 a, float2 b) {
  float2 r;
  r.x = a.x * b.x - a.y * b.y;
  r.y = a.x * b.y + a.y * b.x;
  return r;
}
__device__ __forceinline__ float2 cadd(float2 a, float2 b) {
  float2 r; r.x = a.x + b.x; r.y = a.y + b.y; return r;
}
__device__ __forceinline__ float2 cfma(float2 a, float2 b, float2 c) {
  c.x += a.x * b.x - a.y * b.y;
  c.y += a.x * b.y + a.y * b.x;
  return c;
}
__device__ __forceinline__ ushort f2h(float f) {
  _Float16 h = (_Float16)f;
  return *(ushort*)&h;
}
__device__ __forceinline__ uint pack2h(float a, float b) {
  return (uint)f2h(a) | ((uint)f2h(b) << 16);
}

// ---- DPP-based wave reductions (VALU-speed; avoids ds_bpermute shuffles) ----
template<int CTRL, int RM>
__device__ __forceinline__ float dpp_add(float v) {
  int x = __builtin_amdgcn_update_dpp(0, __float_as_int(v), CTRL, RM, 0xF, false);
  return v + __int_as_float(x);
}
// sum over each consecutive 8-lane group; result in all 8 lanes
__device__ __forceinline__ float red8(float v) {
  v = dpp_add<0xB1, 0xF>(v);    // quad_perm [1,0,3,2]  (xor 1)
  v = dpp_add<0x4E, 0xF>(v);    // quad_perm [2,3,0,1]  (xor 2)
  v = dpp_add<0x141, 0xF>(v);   // row_half_mirror      (xor-pair quads)
  return v;
}
// sum over all 64 lanes; total lands in lane 63 -> broadcast via readlane
__device__ __forceinline__ float red64(float v) {
  v = dpp_add<0x121, 0xF>(v);   // row_ror:1
  v = dpp_add<0x122, 0xF>(v);   // row_ror:2
  v = dpp_add<0x124, 0xF>(v);   // row_ror:4
  v = dpp_add<0x128, 0xF>(v);   // row_ror:8  -> row sums
  v = dpp_add<0x142, 0xA>(v);   // row_bcast15 into rows 1,3
  v = dpp_add<0x143, 0xC>(v);   // row_bcast31 into rows 2,3
  return __int_as_float(__builtin_amdgcn_readlane(__float_as_int(v), 63));
}

// ====== Stage 1: block 0 = kgen; blocks 1..456 = LayerNorm(->fp16) + wconv ======
__global__ __launch_bounds__(576) void stage1_kernel(
    const float* __restrict__ x, const float* __restrict__ nw,
    const float* __restrict__ nb, ushort* __restrict__ xn16,
    const float* __restrict__ lre, const float* __restrict__ lim,
    const float* __restrict__ pre, const float* __restrict__ pim,
    const float* __restrict__ bre, const float* __restrict__ bim,
    const float* __restrict__ cre, const float* __restrict__ cim,
    const float* __restrict__ logstep, float* __restrict__ Kout,
    const float* __restrict__ w1, const float* __restrict__ w2,
    ushort* __restrict__ Wst) {
  __shared__ float2 Ldab[64], Lu[64], Lr[64], LBb[64];
  __shared__ float2 Rv[2048];     // [a*64+n] = (c^T (Ab^32)^a)[n]
  __shared__ float2 Wv[2048];     // [n*32+b] = (Ab^b Bb)[n]
  int tid = threadIdx.x;
  int wv = tid >> 6;              // wave 0..8
  int lane = tid & 63;

  if (blockIdx.x != 0) {
    // ---- LayerNorm: 9 rows per block, one wave per row; fp16 output ----
    int row = (blockIdx.x - 1) * 9 + wv;
    if (row < BSZ * LSEQ) {
      const float* xr = x + (size_t)row * HDIM;
      float4 v0 = ((const float4*)xr)[lane];
      float4 v1 = ((const float4*)xr)[lane + 64];
      float s  = v0.x + v0.y + v0.z + v0.w + v1.x + v1.y + v1.z + v1.w;
      float ss = v0.x*v0.x + v0.y*v0.y + v0.z*v0.z + v0.w*v0.w
               + v1.x*v1.x + v1.y*v1.y + v1.z*v1.z + v1.w*v1.w;
      s  = red64(s);
      ss = red64(ss);
      float mu   = s * (1.0f / HDIM);
      float var  = ss * (1.0f / HDIM) - mu * mu;
      float rstd = rsqrtf(var + 1e-5f);
      float4 w0 = ((const float4*)nw)[lane];
      float4 w1v = ((const float4*)nw)[lane + 64];
      float4 b0 = ((const float4*)nb)[lane];
      float4 b1 = ((const float4*)nb)[lane + 64];
      float4 o0, o1;
      o0.x = (v0.x - mu) * rstd * w0.x + b0.x;
      o0.y = (v0.y - mu) * rstd * w0.y + b0.y;
      o0.z = (v0.z - mu) * rstd * w0.z + b0.z;
      o0.w = (v0.w - mu) * rstd * w0.w + b0.w;
      o1.x = (v1.x - mu) * rstd * w1v.x + b1.x;
      o1.y = (v1.y - mu) * rstd * w1v.y + b1.y;
      o1.z = (v1.z - mu) * rstd * w1v.z + b1.z;
      o1.w = (v1.w - mu) * rstd * w1v.w + b1.w;
      ushort* xo = xn16 + (size_t)row * HDIM;
      uint2 p0, p1;
      p0.x = pack2h(o0.x, o0.y); p0.y = pack2h(o0.z, o0.w);
      p1.x = pack2h(o1.x, o1.y); p1.y = pack2h(o1.z, o1.w);
      *(uint2*)&xo[lane * 4]       = p0;
      *(uint2*)&xo[256 + lane * 4] = p1;
    }
    // ---- Weight convert (fills idle time while block 0 runs kgen) ----
    int idx = (blockIdx.x - 1) * 576 + tid;
    if (idx < 65536) {
      int e0 = idx * 8;
      int n = e0 >> 9, k0 = e0 & 511;
      const float* Wr = (n < 512) ? (w1 + (size_t)n * 512 + k0)
                                  : (w2 + (size_t)(n - 512) * 512 + k0);
      ushort tmp[8];
      #pragma unroll
      for (int q = 0; q < 8; q++) tmp[q] = f2h(Wr[q]);
      *(short8*)&Wst[e0] = *(short8*)tmp;
    }
    return;
  }

  // ================= block 0: K generation =================
  if (tid < 64) {
    int n = tid;
    float step = expf(logstep[0]);
    float g = 2.0f / step;
    float lr = lre[n], li = lim[n];
    float pr = pre[n], pi = pim[n];
    float br = bre[n], bi = bim[n];
    float den  = (g - lr) * (g - lr) + li * li;
    float dinr = (g - lr) / den, dini = li / den;
    float dabr = (g + lr) * dinr - li * dini;
    float dabi = (g + lr) * dini + li * dinr;
    float ur = dinr * pr - dini * pi;
    float ui = dinr * pi + dini * pr;
    float qr = pr * dinr + pi * dini;
    float qi = pr * dini - pi * dinr;
    float pm2 = pr * pr + pi * pi;
    float betr = red64(pm2 * dinr);
    float beti = red64(pm2 * dini);
    float gar  = red64(qr * br - qi * bi);
    float gai  = red64(qr * bi + qi * br);
    float obr = 1.0f + betr, obi = beti;
    float ob2 = obr * obr + obi * obi;
    float kr = -2.0f * g * obr / ob2;
    float ki =  2.0f * g * obi / ob2;
    float rr = kr * qr - ki * qi;
    float ri = kr * qi + ki * qr;
    float tgr = (gar * obr + gai * obi) / ob2;
    float tgi = (gai * obr - gar * obi) / ob2;
    float dbr = dinr * br - dini * bi;
    float dbi = dinr * bi + dini * br;
    float Bbr = 2.0f * (dbr - (ur * tgr - ui * tgi));
    float Bbi = 2.0f * (dbi - (ur * tgi + ui * tgr));
    float2 t;
    t.x = dabr; t.y = dabi; Ldab[n] = t;
    t.x = ur;   t.y = ui;   Lu[n]   = t;
    t.x = rr;   t.y = ri;   Lr[n]   = t;
    t.x = Bbr;  t.y = Bbi;  LBb[n]  = t;
  }
  if (wv == 8) { float2 cc; cc.x = cre[lane]; cc.y = cim[lane]; Rv[lane] = cc; }
  __syncthreads();

  int g8 = lane >> 3;
  int q8 = lane & 7;
  int jm = wv * 8 + g8;
  float2 cv[8];

  if (wv < 8) {
    // Phase B: barrier-free column chains (DPP 8-lane reduces)
    float2 dab[8], u[8], rn[8];
    #pragma unroll
    for (int ii = 0; ii < 8; ii++) {
      int n = q8 * 8 + ii;
      dab[ii] = Ldab[n]; u[ii] = Lu[n]; rn[ii] = Lr[n];
    }
    float2 rj = Lr[jm];
    #pragma unroll
    for (int ii = 0; ii < 8; ii++) {
      int n = q8 * 8 + ii;
      cv[ii] = cmul(u[ii], rj);
      if (n == jm) cv[ii] = cadd(cv[ii], dab[ii]);
    }
    for (int s = 0; s < 31; s++) {
      float2 part; part.x = 0.f; part.y = 0.f;
      #pragma unroll
      for (int ii = 0; ii < 8; ii++) part = cfma(rn[ii], cv[ii], part);
      part.x = red8(part.x);
      part.y = red8(part.y);
      #pragma unroll
      for (int ii = 0; ii < 8; ii++) {
        float2 nc = cmul(dab[ii], cv[ii]);
        cv[ii] = cfma(u[ii], part, nc);
      }
    }
  } else {
    // Phase D (concurrent): W chain (DPP 64-lane reduce, scalar broadcast)
    float2 dab0 = Ldab[lane], u0 = Lu[lane], r0 = Lr[lane];
    float2 w = LBb[lane];
    Wv[lane * 32 + 0] = w;
    for (int b = 1; b < 32; b++) {
      float dr = red64(r0.x * w.x - r0.y * w.y);
      float di = red64(r0.x * w.y + r0.y * w.x);
      float2 nw2;
      nw2.x = dab0.x * w.x - dab0.y * w.y + u0.x * dr - u0.y * di;
      nw2.y = dab0.x * w.y + dab0.y * w.x + u0.x * di + u0.y * dr;
      w = nw2;
      Wv[lane * 32 + b] = w;
    }
  }
  __syncthreads();

  // Phase C: R chain (DPP reduces; one block barrier per step)
  for (int a = 1; a < 32; a++) {
    if (wv < 8) {
      float2 part; part.x = 0.f; part.y = 0.f;
      #pragma unroll
      for (int ii = 0; ii < 8; ii++) {
        float2 Rk = Rv[(a - 1) * 64 + q8 * 8 + ii];
        part = cfma(Rk, cv[ii], part);
      }
      part.x = red8(part.x);
      part.y = red8(part.y);
      if (q8 == 0) Rv[a * 64 + jm] = part;
    }
    __syncthreads();
  }

  // Phase E: K[a*32+b] = Re( R[a] . W[:,b] ); waves 0..7, 4 rows each.
  // R-reads are 2-address wave broadcasts -> ~30x less LDS traffic than before.
  if (wv < 8) {
    int b = lane & 31, half = lane >> 5;
    #pragma unroll
    for (int a = 0; a < 4; a++) {
      int arow = wv * 4 + a;
      float acc = 0.f;
      #pragma unroll
      for (int n = 0; n < 32; n++) {
        float2 W = Wv[(half * 32 + n) * 32 + b];
        float2 R = Rv[arow * 64 + half * 32 + n];
        acc += R.x * W.x - R.y * W.y;
      }
      acc += __shfl_xor(acc, 32);
      if (half == 0) Kout[arow * 32 + b] = acc;
    }
  }
}

// ------- Prep: transpose(xn16->Uhi, fp16 in/out) + toeplitz(K->Thi, guarded) -------
// blocks [0,512): transpose; [512,1024): toeplitz.
__global__ __launch_bounds__(256) void prep_kernel(
    const ushort* __restrict__ xn16, const float* __restrict__ K,
    ushort* __restrict__ Uhi, ushort* __restrict__ Thi) {
  __shared__ __attribute__((aligned(16))) ushort tile[64][72];
  int blk = blockIdx.x;
  int tid = threadIdx.x;
  if (blk < 512) {
    int ht = blk & 7, lt = (blk >> 3) & 15, b = blk >> 7;
    int r = tid >> 2;               // 0..63 (t' within tile)
    int sc = (tid & 3) * 16;        // 0,16,32,48 (h within tile)
    const ushort* src = xn16 + ((size_t)(b * LSEQ + lt * 64 + r)) * HDIM + ht * 64 + sc;
    uint4 va = *(const uint4*)&src[0];
    uint4 vb = *(const uint4*)&src[8];
    *(uint4*)&tile[r][sc]     = va;
    *(uint4*)&tile[r][sc + 8] = vb;
    __syncthreads();
    // output: row = h, cols = t' (16 per thread, packed stores)
    int hr = tid >> 2;              // 0..63 (h within tile)
    int c0 = (tid & 3) * 16;        // t' chunk
    ushort tmp[16];
    #pragma unroll
    for (int q = 0; q < 16; q++) tmp[q] = tile[c0 + q][hr];
    ushort* dst = Uhi + ((size_t)(b * HDIM + ht * 64 + hr)) * LSEQ + lt * 64 + c0;
    *(uint4*)&dst[0] = *(uint4*)&tmp[0];
    *(uint4*)&dst[8] = *(uint4*)&tmp[8];
  } else {
    int r = blk - 512;                              // 0..511
    int t = r * 2 + (tid >> 7);
    int tau0 = (tid & 127) * 8;
    int bound = ((t >> 6) + 1) << 6;                // conv never reads tau >= bound
    if (tau0 < bound) {
      ushort hi[8];
      #pragma unroll
      for (int q = 0; q < 8; q++) {
        int tau = tau0 + q;
        float v = (tau <= t) ? K[t - tau] : 0.f;
        hi[q] = f2h(v);
      }
      *(short8*)&Thi[(size_t)t * 1024 + tau0] = *(short8*)hi;
    }
  }
}

// -------- Conv GEMM: fp16, K_STEP=64, dbuf LDS, depth-1 named-reg prefetch ----
__global__ __launch_bounds__(256) void conv_gemm_kernel(
    const ushort* __restrict__ Thi, const ushort* __restrict__ Uhi,
    const ushort* __restrict__ xn16, const float* __restrict__ dptr,
    ushort* __restrict__ A) {
  // per set: [T][U], each 64 rows x 72 halfs (64 + 8 pad) = 4608 -> 9216 ushorts/set
  __shared__ __attribute__((aligned(16))) ushort sbuf[2 * 9216];
  int tid = threadIdx.x;
  int lane = tid & 63;
  int wv = tid >> 6;
  int wm = wv >> 1, wn = wv & 1;
  int by = blockIdx.y;                    // 0..15
  int bm = (by < 8) ? by : 23 - by;       // balanced pairing across CUs
  int bn = blockIdx.x;                    // 0..31
  floatx4 acc[2][2] = {};
  int srow = tid >> 2;                    // 0..63
  int scol = (tid & 3) * 16;              // 0,16,32,48
  int ldst = srow * 72 + scol;
  int fr = lane & 15, fq = (lane >> 4) * 8;
  size_t Toff = (size_t)(bm * 64 + srow) * 1024 + scol;
  size_t Uoff = (size_t)(bn * 64 + srow) * 1024 + scol;
  int KT = bm + 1;                        // 64-wide k-tiles (tau <= t)
  // ---- prologue: stage tile 0 into set 0 ----
  uint4 t0 = *(const uint4*)&Thi[Toff];
  uint4 t1 = *(const uint4*)&Thi[Toff + 8];
  uint4 u0 = *(const uint4*)&Uhi[Uoff];
  uint4 u1 = *(const uint4*)&Uhi[Uoff + 8];
  *(uint4*)&sbuf[ldst]            = t0;
  *(uint4*)&sbuf[ldst + 8]        = t1;
  *(uint4*)&sbuf[ldst + 4608]     = u0;
  *(uint4*)&sbuf[ldst + 4608 + 8] = u1;
  __syncthreads();
  for (int kt = 0; kt < KT; kt++) {
    const ushort* src = sbuf + (kt & 1) * 9216;
    bool more = (kt + 1 < KT);
    if (more) {
      size_t k1 = (size_t)(kt + 1) * 64;
      t0 = *(const uint4*)&Thi[Toff + k1];
      t1 = *(const uint4*)&Thi[Toff + k1 + 8];
      u0 = *(const uint4*)&Uhi[Uoff + k1];
      u1 = *(const uint4*)&Uhi[Uoff + k1 + 8];
    }
    half8 ah[2][2], bh[2][2];
    #pragma unroll
    for (int i = 0; i < 2; i++) {
      int ar = (wm * 32 + i * 16 + fr) * 72;
      int br = 4608 + (wn * 32 + i * 16 + fr) * 72;
      ah[i][0] = *(const half8*)&src[ar + fq];
      ah[i][1] = *(const half8*)&src[ar + 32 + fq];
      bh[i][0] = *(const half8*)&src[br + fq];
      bh[i][1] = *(const half8*)&src[br + 32 + fq];
    }
    #pragma unroll
    for (int ks = 0; ks < 2; ks++)
      #pragma unroll
      for (int i = 0; i < 2; i++)
        #pragma unroll
        for (int j = 0; j < 2; j++)
          acc[i][j] = __builtin_amdgcn_mfma_f32_16x16x32_f16(ah[i][ks], bh[j][ks], acc[i][j], 0, 0, 0);
    if (more) {
      ushort* dst = sbuf + ((kt & 1) ^ 1) * 9216;
      *(uint4*)&dst[ldst]            = t0;
      *(uint4*)&dst[ldst + 8]        = t1;
      *(uint4*)&dst[ldst + 4608]     = u0;
      *(uint4*)&dst[ldst + 4608 + 8] = u1;
      __syncthreads();
    }
  }
  float d = dptr[0];
  int row0 = bm * 64 + wm * 32;
  int col0 = bn * 64 + wn * 32;
  int fc = lane & 15, frq = (lane >> 4) * 4;
  #pragma unroll
  for (int i = 0; i < 2; i++)
    #pragma unroll
    for (int j = 0; j < 2; j++)
      #pragma unroll
      for (int r = 0; r < 4; r++) {
        int t = row0 + i * 16 + frq + r;
        int c = col0 + j * 16 + fc;
        int b = c >> 9, h = c & 511;
        size_t off = (size_t)(b * LSEQ + t) * HDIM + h;
        float xv = (float)(*(const _Float16*)&xn16[off]);
        float y = acc[i][j][r] + d * xv;
        // gelu(y) = y * sigmoid(2z), z = 0.79788456*(y+0.044715*y^3)
        float z2 = 1.5957691216057308f * y * (1.0f + 0.044715f * y * y);
        float sg = __builtin_amdgcn_rcpf(1.0f + __expf(-z2));
        A[off] = f2h(y * sg);
      }
}

// ---- Proj GEMM: fp16, K_STEP=64, dbuf LDS, depth-1 named-reg prefetch, gated epilogue ----
__global__ __launch_bounds__(256) void proj_kernel(
    const ushort* __restrict__ Abuf, const ushort* __restrict__ Wst,
    const float* __restrict__ x, const float* __restrict__ ob,
    const float* __restrict__ o2b, float* __restrict__ out) {
  // per set: [A][W1][W2], each 64 x 72 halfs = 4608 -> 13824 ushorts/set
  __shared__ __attribute__((aligned(16))) ushort sbuf[2 * 13824];
  int tid = threadIdx.x;
  int lane = tid & 63;
  int wv = tid >> 6;
  int wm = wv >> 1, wn = wv & 1;
  int bm = blockIdx.y, bn = blockIdx.x;   // bm<64, bn<8
  int srow = tid >> 2;                    // 0..63
  int scol = (tid & 3) * 16;              // 0,16,32,48
  int ldst = srow * 72 + scol;
  int fr = lane & 15, fq = (lane >> 4) * 8;
  floatx4 acc1[2][2] = {}, acc2[2][2] = {};
  size_t Aoff  = (size_t)(bm * 64 + srow) * 512 + scol;
  size_t W1off = (size_t)(bn * 64 + srow) * 512 + scol;
  size_t W2off = W1off + (size_t)512 * 512;
  // ---- prologue: stage tile 0 into set 0 ----
  uint4 a0 = *(const uint4*)&Abuf[Aoff];
  uint4 a1 = *(const uint4*)&Abuf[Aoff + 8];
  uint4 v0 = *(const uint4*)&Wst[W1off];
  uint4 v1 = *(const uint4*)&Wst[W1off + 8];
  uint4 v2 = *(const uint4*)&Wst[W2off];
  uint4 v3 = *(const uint4*)&Wst[W2off + 8];
  *(uint4*)&sbuf[ldst]            = a0;
  *(uint4*)&sbuf[ldst + 8]        = a1;
  *(uint4*)&sbuf[ldst + 4608]     = v0;
  *(uint4*)&sbuf[ldst + 4608 + 8] = v1;
  *(uint4*)&sbuf[ldst + 9216]     = v2;
  *(uint4*)&sbuf[ldst + 9216 + 8] = v3;
  __syncthreads();
  for (int kt = 0; kt < 8; kt++) {
    const ushort* src = sbuf + (kt & 1) * 13824;
    bool more = (kt + 1 < 8);
    if (more) {
      int k1 = (kt + 1) * 64;
      a0 = *(const uint4*)&Abuf[Aoff + k1];
      a1 = *(const uint4*)&Abuf[Aoff + k1 + 8];
      v0 = *(const uint4*)&Wst[W1off + k1];
      v1 = *(const uint4*)&Wst[W1off + k1 + 8];
      v2 = *(const uint4*)&Wst[W2off + k1];
      v3 = *(const uint4*)&Wst[W2off + k1 + 8];
    }
    half8 af[2][2], b1[2][2], b2[2][2];
    #pragma unroll
    for (int i = 0; i < 2; i++) {
      int ar  = (wm * 32 + i * 16 + fr) * 72;
      int wr1 = 4608 + (wn * 32 + i * 16 + fr) * 72;
      int wr2 = 9216 + (wn * 32 + i * 16 + fr) * 72;
      af[i][0] = *(const half8*)&src[ar + fq];
      af[i][1] = *(const half8*)&src[ar + 32 + fq];
      b1[i][0] = *(const half8*)&src[wr1 + fq];
      b1[i][1] = *(const half8*)&src[wr1 + 32 + fq];
      b2[i][0] = *(const half8*)&src[wr2 + fq];
      b2[i][1] = *(const half8*)&src[wr2 + 32 + fq];
    }
    #pragma unroll
    for (int ks = 0; ks < 2; ks++)
      #pragma unroll
      for (int i = 0; i < 2; i++)
        #pragma unroll
        for (int j = 0; j < 2; j++) {
          acc1[i][j] = __builtin_amdgcn_mfma_f32_16x16x32_f16(af[i][ks], b1[j][ks], acc1[i][j], 0, 0, 0);
          acc2[i][j] = __builtin_amdgcn_mfma_f32_16x16x32_f16(af[i][ks], b2[j][ks], acc2[i][j], 0, 0, 0);
        }
    if (more) {
      ushort* dst = sbuf + ((kt & 1) ^ 1) * 13824;
      *(uint4*)&dst[ldst]            = a0;
      *(uint4*)&dst[ldst + 8]        = a1;
      *(uint4*)&dst[ldst + 4608]     = v0;
      *(uint4*)&dst[ldst + 4608 + 8] = v1;
      *(uint4*)&dst[ldst + 9216]     = v2;
      *(uint4*)&dst[ldst + 9216 + 8] = v3;
      __syncthreads();
    }
  }
  int row0 = bm * 64 + wm * 32;
  int col0 = bn * 64 + wn * 32;
  int fc = lane & 15, frq = (lane >> 4) * 4;
  #pragma unroll
  for (int i = 0; i < 2; i++)
    #pragma unroll
    for (int j = 0; j < 2; j++)
      #pragma unroll
      for (int r = 0; r < 4; r++) {
        int row = row0 + i * 16 + frq + r;
        int col = col0 + j * 16 + fc;
        float c1 = acc1[i][j][r] + ob[col];
        float c2 = acc2[i][j][r] + o2b[col];
        float gate = __builtin_amdgcn_rcpf(1.0f + __expf(-c2));
        size_t off = (size_t)row * HDIM + col;
        out[off] = x[off] + c1 * gate;
      }
}

extern "C" void kernel_launch(void* const* d_in, const int* in_sizes, int n_in,
                              void* d_out, int out_size, void* d_ws, size_t ws_size,
                              hipStream_t stream) {
  const float* x   = (const float*)d_in[0];
  const float* nw  = (const float*)d_in[1];
  const float* nb  = (const float*)d_in[2];
  const float* lre = (const float*)d_in[3];
  const float* lim = (const float*)d_in[4];
  const float* pre = (const float*)d_in[5];
  const float* pim = (const float*)d_in[6];
  const float* bre = (const float*)d_in[7];
  const float* bim = (const float*)d_in[8];
  const float* cre = (const float*)d_in[9];
  const float* cim = (const float*)d_in[10];
  const float* dsc = (const float*)d_in[11];
  const float* lst = (const float*)d_in[12];
  const float* w1  = (const float*)d_in[13];
  const float* ob  = (const float*)d_in[14];
  const float* w2  = (const float*)d_in[15];
  const float* o2b = (const float*)d_in[16];

  char* ws = (char*)d_ws;
  ushort* xn16 = (ushort*)(ws);                         // 0..4MB  (fp16 LN output)
  ushort* Uhi  = (ushort*)(ws + (size_t)(8  << 20));    // 8..12MB  (fp16)
  ushort* Thi  = (ushort*)(ws + (size_t)(12 << 20));    // 12..14MB (fp16)
  ushort* Wst  = (ushort*)(ws + (size_t)(16 << 20));    // 16..17MB (fp16)
  ushort* Abuf = (ushort*)(ws + (size_t)(17 << 20));    // 17..21MB (fp16)
  float* Kbuf  = (float*)(ws + (size_t)(21 << 20));     // 4KB
  float* out   = (float*)d_out;

  stage1_kernel<<<dim3(457), dim3(576), 0, stream>>>(x, nw, nb, xn16,
                                                     lre, lim, pre, pim, bre, bim,
                                                     cre, cim, lst, Kbuf,
                                                     w1, w2, Wst);
  prep_kernel<<<dim3(1024), dim3(256), 0, stream>>>(xn16, Kbuf, Uhi, Thi);
  conv_gemm_kernel<<<dim3(32, 16), dim3(256), 0, stream>>>(Thi, Uhi,
                                                           xn16, dsc, Abuf);
  proj_kernel<<<dim3(8, 64), dim3(256), 0, stream>>>(Abuf, Wst, x, ob, o2b, out);
}